// Round 1
// baseline (357.130 us; speedup 1.0000x reference)
//
#include <hip/hip_runtime.h>
#include <hip/hip_bf16.h>

#define CHN 16
#define RF 9
#define RRP 5              // ceil(RF/2) packed freq-pairs
#define HWDIM 256
#define POSN (HWDIM * HWDIM)

__device__ __forceinline__ float bflo(uint32_t v) { return __uint_as_float(v << 16); }
__device__ __forceinline__ float bfhi(uint32_t v) { return __uint_as_float(v & 0xffff0000u); }

__device__ __forceinline__ uint16_t f32_to_bf16(float f) {
    uint32_t u = __float_as_uint(f);
    uint32_t rounding = 0x7fffu + ((u >> 16) & 1u);
    u += rounding;
    return (uint16_t)(u >> 16);
}

// ws layout per plane: [pos (65536)][rr (5)][cc (16)] of u32 = {bf16 r=2rr (lo), bf16 r=2rr+1 (hi)}
// linear thread order: (p, rr, cc, pos) with pos fastest -> coalesced reads of P.
__global__ void transpose_pack(const float* __restrict__ Pu,
                               const float* __restrict__ Pv,
                               const float* __restrict__ Pw,
                               uint32_t* __restrict__ ws) {
    int tid = blockIdx.x * blockDim.x + threadIdx.x;   // 3*5*16*65536 = 15,728,640 threads
    int pos = tid & (POSN - 1);
    int t = tid >> 16;          // p*80 + rr*16 + cc
    int cc = t & 15;
    int prr = t >> 4;           // p*5 + rr
    int rr = prr % RRP;
    int p = prr / RRP;
    const float* P = (p == 0) ? Pu : ((p == 1) ? Pv : Pw);
    int r0 = 2 * rr;
    int r1 = r0 + 1;
    float v0 = P[(cc * RF + r0) * POSN + pos];
    float v1 = (r1 < RF) ? P[(cc * RF + r1) * POSN + pos] : 0.0f;
    uint32_t packed = (uint32_t)f32_to_bf16(v0) | ((uint32_t)f32_to_bf16(v1) << 16);
    ws[((size_t)((size_t)p * POSN + pos) * RRP + rr) * CHN + cc] = packed;
}

__global__ __launch_bounds__(256) void triplane_main(const float* __restrict__ coords,
                                                     const uint32_t* __restrict__ ws,
                                                     float* __restrict__ out, int N) {
    int tid = blockIdx.x * blockDim.x + threadIdx.x;
    int n = tid >> 4;
    if (n >= N) return;
    int cc = tid & 15;
    float c0 = coords[3 * n + 0];
    float c1 = coords[3 * n + 1];
    float c2 = coords[3 * n + 2];
    float acc = 0.f;
#pragma unroll
    for (int p = 0; p < 3; ++p) {
        // plane u: gx=c1, gy=c2, ci=c0 ; plane v: gx=c0, gy=c2, ci=c1 ; plane w: gx=c0, gy=c1, ci=c2
        float gx = (p == 0) ? c1 : c0;
        float gy = (p == 2) ? c1 : c2;
        float ci = (p == 0) ? c0 : ((p == 1) ? c1 : c2);

        float ix = (gx + 1.f) * 127.5f;   // * 0.5 * (W-1)
        float iy = (gy + 1.f) * 127.5f;
        float x0f = floorf(ix), y0f = floorf(iy);
        float wx = ix - x0f, wy = iy - y0f;
        int x0 = (int)x0f; x0 = max(0, min(x0, HWDIM - 1));
        int y0 = (int)y0f; y0 = max(0, min(y0, HWDIM - 1));
        int x1 = min(x0 + 1, HWDIM - 1);
        int y1 = min(y0 + 1, HWDIM - 1);

        float cv = (ci + 1.f) * 127.5f + 0.5f;   // c + 0.5
        float bas[RF];
#pragma unroll
        for (int r = 0; r < RF; ++r) {
            const float k = 3.14159265358979f * ((float)(1 << r) - 0.5f) / 512.f;
            bas[r] = __cosf(cv * k);
        }

        const uint32_t* Pl = ws + (size_t)p * POSN * RRP * CHN;
        float w00 = (1.f - wx) * (1.f - wy);
        float w01 = wx * (1.f - wy);
        float w10 = (1.f - wx) * wy;
        float w11 = wx * wy;
        int p00 = y0 * HWDIM + x0;
        int p01 = y0 * HWDIM + x1;
        int p10 = y1 * HWDIM + x0;
        int p11 = y1 * HWDIM + x1;

        float s00 = 0.f, s01 = 0.f, s10 = 0.f, s11 = 0.f;
#pragma unroll
        for (int rr = 0; rr < RRP; ++rr) {
            int off = rr * CHN + cc;
            uint32_t v00 = Pl[(size_t)p00 * (RRP * CHN) + off];
            uint32_t v01 = Pl[(size_t)p01 * (RRP * CHN) + off];
            uint32_t v10 = Pl[(size_t)p10 * (RRP * CHN) + off];
            uint32_t v11 = Pl[(size_t)p11 * (RRP * CHN) + off];
            float bl = bas[2 * rr];
            s00 = fmaf(bl, bflo(v00), s00);
            s01 = fmaf(bl, bflo(v01), s01);
            s10 = fmaf(bl, bflo(v10), s10);
            s11 = fmaf(bl, bflo(v11), s11);
            if (2 * rr + 1 < RF) {
                float bh = bas[2 * rr + 1];
                s00 = fmaf(bh, bfhi(v00), s00);
                s01 = fmaf(bh, bfhi(v01), s01);
                s10 = fmaf(bh, bfhi(v10), s10);
                s11 = fmaf(bh, bfhi(v11), s11);
            }
        }
        acc += w00 * s00 + w01 * s01 + w10 * s10 + w11 * s11;
    }
    out[(size_t)n * CHN + cc] = 2.f * acc;
}

// Fallback (ws too small): direct gather from original (C,H,W) f32 layout. Slow but correct.
__global__ __launch_bounds__(256) void triplane_direct(const float* __restrict__ coords,
                                                       const float* __restrict__ Pu,
                                                       const float* __restrict__ Pv,
                                                       const float* __restrict__ Pw,
                                                       float* __restrict__ out, int N) {
    int tid = blockIdx.x * blockDim.x + threadIdx.x;
    int n = tid >> 4;
    if (n >= N) return;
    int cc = tid & 15;
    float c0 = coords[3 * n + 0];
    float c1 = coords[3 * n + 1];
    float c2 = coords[3 * n + 2];
    float acc = 0.f;
#pragma unroll
    for (int p = 0; p < 3; ++p) {
        const float* P = (p == 0) ? Pu : ((p == 1) ? Pv : Pw);
        float gx = (p == 0) ? c1 : c0;
        float gy = (p == 2) ? c1 : c2;
        float ci = (p == 0) ? c0 : ((p == 1) ? c1 : c2);
        float ix = (gx + 1.f) * 127.5f;
        float iy = (gy + 1.f) * 127.5f;
        float x0f = floorf(ix), y0f = floorf(iy);
        float wx = ix - x0f, wy = iy - y0f;
        int x0 = (int)x0f; x0 = max(0, min(x0, HWDIM - 1));
        int y0 = (int)y0f; y0 = max(0, min(y0, HWDIM - 1));
        int x1 = min(x0 + 1, HWDIM - 1);
        int y1 = min(y0 + 1, HWDIM - 1);
        float cv = (ci + 1.f) * 127.5f + 0.5f;
        float w00 = (1.f - wx) * (1.f - wy);
        float w01 = wx * (1.f - wy);
        float w10 = (1.f - wx) * wy;
        float w11 = wx * wy;
        int p00 = y0 * HWDIM + x0;
        int p01 = y0 * HWDIM + x1;
        int p10 = y1 * HWDIM + x0;
        int p11 = y1 * HWDIM + x1;
#pragma unroll
        for (int r = 0; r < RF; ++r) {
            const float k = 3.14159265358979f * ((float)(1 << r) - 0.5f) / 512.f;
            float b = __cosf(cv * k);
            const float* Pc = P + (size_t)(cc * RF + r) * POSN;
            float v = w00 * Pc[p00] + w01 * Pc[p01] + w10 * Pc[p10] + w11 * Pc[p11];
            acc = fmaf(b, v, acc);
        }
    }
    out[(size_t)n * CHN + cc] = 2.f * acc;
}

extern "C" void kernel_launch(void* const* d_in, const int* in_sizes, int n_in,
                              void* d_out, int out_size, void* d_ws, size_t ws_size,
                              hipStream_t stream) {
    const float* coords = (const float*)d_in[0];
    const float* Pu = (const float*)d_in[1];
    const float* Pv = (const float*)d_in[2];
    const float* Pw = (const float*)d_in[3];
    float* out = (float*)d_out;
    int N = in_sizes[0] / 3;

    size_t need = (size_t)3 * POSN * RRP * CHN * sizeof(uint32_t);   // ~63 MB
    if (ws_size >= need) {
        uint32_t* ws = (uint32_t*)d_ws;
        int tt = 3 * RRP * CHN * POSN;                 // 15,728,640
        transpose_pack<<<tt / 256, 256, 0, stream>>>(Pu, Pv, Pw, ws);
        int threads = N * CHN;
        triplane_main<<<(threads + 255) / 256, 256, 0, stream>>>(coords, ws, out, N);
    } else {
        int threads = N * CHN;
        triplane_direct<<<(threads + 255) / 256, 256, 0, stream>>>(coords, Pu, Pv, Pw, out, N);
    }
}

// Round 2
// 193.465 us; speedup vs baseline: 1.8460x; 1.8460x over previous
//
#include <hip/hip_runtime.h>
#include <hip/hip_bf16.h>

#define CHN 16
#define RF 9
#define HWDIM 256
#define POSN (HWDIM * HWDIM)
#define NBINS 32768   // 5 bits per axis, 3D Morton

__device__ __forceinline__ float bflo(uint32_t v) { return __uint_as_float(v << 16); }
__device__ __forceinline__ float bfhi(uint32_t v) { return __uint_as_float(v & 0xffff0000u); }

__device__ __forceinline__ uint32_t f32_to_bf16(float f) {
    uint32_t u = __float_as_uint(f);
    u += 0x7fffu + ((u >> 16) & 1u);
    return u >> 16;
}

// ---------- pass 1: transpose/pack ----------
// A layout: [p][pos][cc] as uint4  = freqs r0..r7 packed bf16 pairs (16 B per (pos,cc))
// B layout: [p][pos][cc>>1] as u32 = freq r8 for channel pair (lo=even cc, hi=odd cc)
__global__ __launch_bounds__(256) void transpose_pack2(const float* __restrict__ Pu,
                                                       const float* __restrict__ Pv,
                                                       const float* __restrict__ Pw,
                                                       uint4* __restrict__ A,
                                                       uint32_t* __restrict__ B) {
    int tid = blockIdx.x * blockDim.x + threadIdx.x;   // 3 * 65536 threads
    int pos = tid & (POSN - 1);
    int p = tid >> 16;
    const float* P = (p == 0) ? Pu : ((p == 1) ? Pv : Pw);
    uint32_t r8[8];
    uint4* Ap = A + ((size_t)p * POSN + pos) * CHN;
#pragma unroll
    for (int cc = 0; cc < CHN; ++cc) {
        const float* Pc = P + (size_t)(cc * RF) * POSN + pos;   // reads coalesced across lanes (pos = lane)
        uint32_t w[4];
#pragma unroll
        for (int j = 0; j < 4; ++j) {
            float v0 = Pc[(size_t)(2 * j) * POSN];
            float v1 = Pc[(size_t)(2 * j + 1) * POSN];
            w[j] = f32_to_bf16(v0) | (f32_to_bf16(v1) << 16);
        }
        Ap[cc] = make_uint4(w[0], w[1], w[2], w[3]);
        uint32_t b8 = f32_to_bf16(Pc[(size_t)8 * POSN]);
        if (cc & 1) r8[cc >> 1] |= (b8 << 16); else r8[cc >> 1] = b8;
    }
    uint32_t* Bp = B + ((size_t)p * POSN + pos) * 8;
#pragma unroll
    for (int j = 0; j < 8; ++j) Bp[j] = r8[j];
}

// ---------- pass 2: Morton binning ----------
__device__ __forceinline__ uint32_t part1by2(uint32_t x) {
    x &= 0x3ffu;
    x = (x | (x << 16)) & 0x030000FFu;
    x = (x | (x << 8))  & 0x0300F00Fu;
    x = (x | (x << 4))  & 0x030C30C3u;
    x = (x | (x << 2))  & 0x09249249u;
    return x;
}
__device__ __forceinline__ uint32_t morton_key(float c0, float c1, float c2) {
    int q0 = min(31, max(0, (int)((c0 + 1.f) * 16.f)));
    int q1 = min(31, max(0, (int)((c1 + 1.f) * 16.f)));
    int q2 = min(31, max(0, (int)((c2 + 1.f) * 16.f)));
    return (part1by2((uint32_t)q0) << 2) | (part1by2((uint32_t)q1) << 1) | part1by2((uint32_t)q2);
}

__global__ __launch_bounds__(256) void hist_kernel(const float* __restrict__ coords,
                                                   uint32_t* __restrict__ hist, int N) {
    int n = blockIdx.x * blockDim.x + threadIdx.x;
    if (n >= N) return;
    float c0 = coords[3 * n], c1 = coords[3 * n + 1], c2 = coords[3 * n + 2];
    atomicAdd(&hist[morton_key(c0, c1, c2)], 1u);
}

__global__ __launch_bounds__(1024) void scan_kernel(uint32_t* __restrict__ hist) {
    __shared__ uint32_t part[1024];
    int t = threadIdx.x;
    uint32_t loc[32];
    uint32_t s = 0;
    int base = t * 32;
#pragma unroll
    for (int i = 0; i < 32; ++i) { loc[i] = hist[base + i]; s += loc[i]; }
    part[t] = s;
    __syncthreads();
    for (int off = 1; off < 1024; off <<= 1) {
        uint32_t v = (t >= off) ? part[t - off] : 0u;
        __syncthreads();
        part[t] += v;
        __syncthreads();
    }
    uint32_t run = part[t] - s;   // exclusive base of this 32-chunk
#pragma unroll
    for (int i = 0; i < 32; ++i) { hist[base + i] = run; run += loc[i]; }
}

__global__ __launch_bounds__(256) void scatter_kernel(const float* __restrict__ coords,
                                                      uint32_t* __restrict__ hist,
                                                      float4* __restrict__ sorted, int N) {
    int n = blockIdx.x * blockDim.x + threadIdx.x;
    if (n >= N) return;
    float c0 = coords[3 * n], c1 = coords[3 * n + 1], c2 = coords[3 * n + 2];
    uint32_t key = morton_key(c0, c1, c2);
    uint32_t dst = atomicAdd(&hist[key], 1u);
    sorted[dst] = make_float4(c0, c1, c2, __uint_as_float((uint32_t)n));
}

// ---------- pass 3: main ----------
__global__ __launch_bounds__(256) void triplane_sorted(const float4* __restrict__ sorted,
                                                       const uint4* __restrict__ A,
                                                       const uint32_t* __restrict__ B,
                                                       float* __restrict__ out, int N, int nblk) {
    __shared__ float bas[16][27];
    __shared__ float4 pts[16];
    int blk = blockIdx.x;
    if ((nblk & 7) == 0) {                      // XCD-chunked swizzle: each XCD gets a contiguous Morton range
        int cpx = nblk >> 3;
        blk = (blk & 7) * cpx + (blk >> 3);
    }
    int base = blk * 16;
    int t = threadIdx.x;
    if (t < 16) {
        int i = base + t;
        pts[t] = (i < N) ? sorted[i] : make_float4(0.f, 0.f, 0.f, __uint_as_float(0u));
    }
    __syncthreads();
    if (t < 144) {   // (pt, r): compute basis for all 3 planes; shared across the 16 channel-lanes
        int pt = t / 9, r = t - pt * 9;
        float4 c = pts[pt];
        float k = 3.14159265358979f * ((float)(1 << r) - 0.5f) * (1.f / 512.f);
        bas[pt][0 * 9 + r] = __cosf(((c.x + 1.f) * 127.5f + 0.5f) * k);
        bas[pt][1 * 9 + r] = __cosf(((c.y + 1.f) * 127.5f + 0.5f) * k);
        bas[pt][2 * 9 + r] = __cosf(((c.z + 1.f) * 127.5f + 0.5f) * k);
    }
    __syncthreads();
    int pt = t >> 4, cc = t & 15;
    int gi = base + pt;
    if (gi >= N) return;
    float4 c = pts[pt];
    float acc = 0.f;
#pragma unroll
    for (int p = 0; p < 3; ++p) {
        float gx = (p == 0) ? c.y : c.x;
        float gy = (p == 2) ? c.y : c.z;
        float ix = (gx + 1.f) * 127.5f;
        float iy = (gy + 1.f) * 127.5f;
        float x0f = floorf(ix), y0f = floorf(iy);
        float wx = ix - x0f, wy = iy - y0f;
        int x0 = (int)x0f; x0 = max(0, min(x0, HWDIM - 1));
        int y0 = (int)y0f; y0 = max(0, min(y0, HWDIM - 1));
        int x1 = min(x0 + 1, HWDIM - 1);
        int y1 = min(y0 + 1, HWDIM - 1);
        float b[9];
#pragma unroll
        for (int r = 0; r < 9; ++r) b[r] = bas[pt][p * 9 + r];
        const uint4* Ap = A + (size_t)p * POSN * CHN;
        const uint32_t* Bp = B + (size_t)p * POSN * 8;
        int pos4[4] = { y0 * HWDIM + x0, y0 * HWDIM + x1, y1 * HWDIM + x0, y1 * HWDIM + x1 };
        float w4[4] = { (1.f - wx) * (1.f - wy), wx * (1.f - wy), (1.f - wx) * wy, wx * wy };
        float ps = 0.f;
#pragma unroll
        for (int k = 0; k < 4; ++k) {
            uint4 a = Ap[(size_t)pos4[k] * CHN + cc];          // 16 lanes of a point read 256 B contiguous
            uint32_t bw = Bp[(size_t)pos4[k] * 8 + (cc >> 1)];
            float s;
            s = b[0] * bflo(a.x);          s = fmaf(b[1], bfhi(a.x), s);
            s = fmaf(b[2], bflo(a.y), s);  s = fmaf(b[3], bfhi(a.y), s);
            s = fmaf(b[4], bflo(a.z), s);  s = fmaf(b[5], bfhi(a.z), s);
            s = fmaf(b[6], bflo(a.w), s);  s = fmaf(b[7], bfhi(a.w), s);
            float v8 = (cc & 1) ? bfhi(bw) : bflo(bw);
            s = fmaf(b[8], v8, s);
            ps = fmaf(w4[k], s, ps);
        }
        acc += ps;
    }
    uint32_t n = __float_as_uint(c.w);
    out[(size_t)n * CHN + cc] = 2.f * acc;
}

// ---------- fallback: direct gather from (C,H,W) f32 ----------
__global__ __launch_bounds__(256) void triplane_direct(const float* __restrict__ coords,
                                                       const float* __restrict__ Pu,
                                                       const float* __restrict__ Pv,
                                                       const float* __restrict__ Pw,
                                                       float* __restrict__ out, int N) {
    int tid = blockIdx.x * blockDim.x + threadIdx.x;
    int n = tid >> 4;
    if (n >= N) return;
    int cc = tid & 15;
    float c0 = coords[3 * n + 0];
    float c1 = coords[3 * n + 1];
    float c2 = coords[3 * n + 2];
    float acc = 0.f;
#pragma unroll
    for (int p = 0; p < 3; ++p) {
        const float* P = (p == 0) ? Pu : ((p == 1) ? Pv : Pw);
        float gx = (p == 0) ? c1 : c0;
        float gy = (p == 2) ? c1 : c2;
        float ci = (p == 0) ? c0 : ((p == 1) ? c1 : c2);
        float ix = (gx + 1.f) * 127.5f;
        float iy = (gy + 1.f) * 127.5f;
        float x0f = floorf(ix), y0f = floorf(iy);
        float wx = ix - x0f, wy = iy - y0f;
        int x0 = (int)x0f; x0 = max(0, min(x0, HWDIM - 1));
        int y0 = (int)y0f; y0 = max(0, min(y0, HWDIM - 1));
        int x1 = min(x0 + 1, HWDIM - 1);
        int y1 = min(y0 + 1, HWDIM - 1);
        float cv = (ci + 1.f) * 127.5f + 0.5f;
        float w00 = (1.f - wx) * (1.f - wy), w01 = wx * (1.f - wy);
        float w10 = (1.f - wx) * wy, w11 = wx * wy;
        int p00 = y0 * HWDIM + x0, p01 = y0 * HWDIM + x1;
        int p10 = y1 * HWDIM + x0, p11 = y1 * HWDIM + x1;
#pragma unroll
        for (int r = 0; r < RF; ++r) {
            const float k = 3.14159265358979f * ((float)(1 << r) - 0.5f) / 512.f;
            float b = __cosf(cv * k);
            const float* Pc = P + (size_t)(cc * RF + r) * POSN;
            float v = w00 * Pc[p00] + w01 * Pc[p01] + w10 * Pc[p10] + w11 * Pc[p11];
            acc = fmaf(b, v, acc);
        }
    }
    out[(size_t)n * CHN + cc] = 2.f * acc;
}

extern "C" void kernel_launch(void* const* d_in, const int* in_sizes, int n_in,
                              void* d_out, int out_size, void* d_ws, size_t ws_size,
                              hipStream_t stream) {
    const float* coords = (const float*)d_in[0];
    const float* Pu = (const float*)d_in[1];
    const float* Pv = (const float*)d_in[2];
    const float* Pw = (const float*)d_in[3];
    float* out = (float*)d_out;
    int N = in_sizes[0] / 3;

    size_t offA = 0;
    size_t szA = (size_t)3 * POSN * CHN * sizeof(uint4);        // 48 MB
    size_t offB = offA + szA;
    size_t szB = (size_t)3 * POSN * 8 * sizeof(uint32_t);       // 6 MB
    size_t offS = offB + szB;
    size_t szS = (size_t)N * sizeof(float4);                    // 8 MB @ N=524288
    size_t offH = offS + szS;
    size_t szH = (size_t)NBINS * sizeof(uint32_t);              // 128 KB
    size_t need = offH + szH;

    if (ws_size >= need) {
        char* ws = (char*)d_ws;
        uint4* A = (uint4*)(ws + offA);
        uint32_t* B = (uint32_t*)(ws + offB);
        float4* sorted = (float4*)(ws + offS);
        uint32_t* hist = (uint32_t*)(ws + offH);

        transpose_pack2<<<(3 * POSN) / 256, 256, 0, stream>>>(Pu, Pv, Pw, A, B);

        hipMemsetAsync(hist, 0, szH, stream);
        hist_kernel<<<(N + 255) / 256, 256, 0, stream>>>(coords, hist, N);
        scan_kernel<<<1, 1024, 0, stream>>>(hist);
        scatter_kernel<<<(N + 255) / 256, 256, 0, stream>>>(coords, hist, sorted, N);

        int nblk = (N + 15) / 16;
        triplane_sorted<<<nblk, 256, 0, stream>>>(sorted, A, B, out, N, nblk);
    } else {
        int threads = N * CHN;
        triplane_direct<<<(threads + 255) / 256, 256, 0, stream>>>(coords, Pu, Pv, Pw, out, N);
    }
}

// Round 3
// 171.984 us; speedup vs baseline: 2.0765x; 1.1249x over previous
//
#include <hip/hip_runtime.h>
#include <hip/hip_bf16.h>

#define CHN 16
#define RF 9
#define HWDIM 256
#define POSN (HWDIM * HWDIM)
#define NBINS 32768   // 5 bits per axis, 3D Morton

typedef _Float16 half2_t __attribute__((ext_vector_type(2)));

__device__ __forceinline__ half2_t u2h(uint32_t u) {
    union { uint32_t u; half2_t h; } x; x.u = u; return x.h;
}
__device__ __forceinline__ uint32_t f2h(float f) {
    union { _Float16 h; uint16_t u; } x; x.h = (_Float16)f; return (uint32_t)x.u;
}
__device__ __forceinline__ float h2f(uint32_t u) {
    union { uint16_t u; _Float16 h; } x; x.u = (uint16_t)u; return (float)x.h;
}

#if __has_builtin(__builtin_amdgcn_fdot2)
__device__ __forceinline__ float DOT2(half2_t a, half2_t b, float c) {
    return __builtin_amdgcn_fdot2(a, b, c, false);
}
#else
__device__ __forceinline__ float DOT2(half2_t a, half2_t b, float c) {
    return fmaf((float)a.x, (float)b.x, fmaf((float)a.y, (float)b.y, c));
}
#endif

// ---------- Morton helpers ----------
__device__ __forceinline__ uint32_t part1by2(uint32_t x) {
    x &= 0x3ffu;
    x = (x | (x << 16)) & 0x030000FFu;
    x = (x | (x << 8))  & 0x0300F00Fu;
    x = (x | (x << 4))  & 0x030C30C3u;
    x = (x | (x << 2))  & 0x09249249u;
    return x;
}
__device__ __forceinline__ uint32_t morton_key(float c0, float c1, float c2) {
    int q0 = min(31, max(0, (int)((c0 + 1.f) * 16.f)));
    int q1 = min(31, max(0, (int)((c1 + 1.f) * 16.f)));
    int q2 = min(31, max(0, (int)((c2 + 1.f) * 16.f)));
    return (part1by2((uint32_t)q0) << 2) | (part1by2((uint32_t)q1) << 1) | part1by2((uint32_t)q2);
}

// ---------- pass 1: transpose/pack to f16 (+ fused histogram) ----------
// A: [p][pos][cc] uint4 = f16 freqs r0..r7 packed in pairs (16 B per (pos,cc))
// B: [p][pos][cc>>1] u32 = f16 r8 for channel pair (lo=even cc, hi=odd cc)
__global__ __launch_bounds__(256) void prep_kernel(const float* __restrict__ Pu,
                                                   const float* __restrict__ Pv,
                                                   const float* __restrict__ Pw,
                                                   uint4* __restrict__ A,
                                                   uint32_t* __restrict__ B,
                                                   const float* __restrict__ coords,
                                                   uint32_t* __restrict__ hist,
                                                   int N, int tblk) {
    int b = blockIdx.x;
    if (b < tblk) {
        int tid = b * 256 + threadIdx.x;   // 3 * 65536 threads
        int pos = tid & (POSN - 1);
        int p = tid >> 16;
        const float* P = (p == 0) ? Pu : ((p == 1) ? Pv : Pw);
        uint32_t r8pk[8];
        uint4* Ap = A + ((size_t)p * POSN + pos) * CHN;
#pragma unroll
        for (int cc = 0; cc < CHN; ++cc) {
            const float* Pc = P + (size_t)(cc * RF) * POSN + pos;   // coalesced across lanes
            uint32_t w[4];
#pragma unroll
            for (int j = 0; j < 4; ++j) {
                float v0 = Pc[(size_t)(2 * j) * POSN];
                float v1 = Pc[(size_t)(2 * j + 1) * POSN];
                w[j] = f2h(v0) | (f2h(v1) << 16);
            }
            Ap[cc] = make_uint4(w[0], w[1], w[2], w[3]);
            uint32_t h8 = f2h(Pc[(size_t)8 * POSN]);
            if (cc & 1) r8pk[cc >> 1] |= (h8 << 16); else r8pk[cc >> 1] = h8;
        }
        uint32_t* Bp = B + ((size_t)p * POSN + pos) * 8;
#pragma unroll
        for (int j = 0; j < 8; ++j) Bp[j] = r8pk[j];
    } else {
        int n = (b - tblk) * 256 + threadIdx.x;
        if (n < N) {
            float c0 = coords[3 * n], c1 = coords[3 * n + 1], c2 = coords[3 * n + 2];
            atomicAdd(&hist[morton_key(c0, c1, c2)], 1u);
        }
    }
}

__global__ __launch_bounds__(1024) void scan_kernel(uint32_t* __restrict__ hist) {
    __shared__ uint32_t part[1024];
    int t = threadIdx.x;
    uint32_t loc[32];
    uint32_t s = 0;
    int base = t * 32;
#pragma unroll
    for (int i = 0; i < 32; ++i) { loc[i] = hist[base + i]; s += loc[i]; }
    part[t] = s;
    __syncthreads();
    for (int off = 1; off < 1024; off <<= 1) {
        uint32_t v = (t >= off) ? part[t - off] : 0u;
        __syncthreads();
        part[t] += v;
        __syncthreads();
    }
    uint32_t run = part[t] - s;
#pragma unroll
    for (int i = 0; i < 32; ++i) { hist[base + i] = run; run += loc[i]; }
}

__global__ __launch_bounds__(256) void scatter_kernel(const float* __restrict__ coords,
                                                      uint32_t* __restrict__ hist,
                                                      float4* __restrict__ sorted, int N) {
    int n = blockIdx.x * blockDim.x + threadIdx.x;
    if (n >= N) return;
    float c0 = coords[3 * n], c1 = coords[3 * n + 1], c2 = coords[3 * n + 2];
    uint32_t key = morton_key(c0, c1, c2);
    uint32_t dst = atomicAdd(&hist[key], 1u);
    sorted[dst] = make_float4(c0, c1, c2, __uint_as_float((uint32_t)n));
}

// ---------- pass 3: main ----------
// meta[pt][p]: [0..3] f16x2 basis pairs r0..7, [4] b8 (f32 bits),
//              [5..8] bilinear weights (f32 bits), [9..12] corner byte offsets (pos*256)
__global__ __launch_bounds__(256) void triplane_f16(const float4* __restrict__ sorted,
                                                    const uint4* __restrict__ A,
                                                    const uint32_t* __restrict__ B,
                                                    float* __restrict__ out, int N, int nblk) {
    __shared__ float4 pts[16];
    __shared__ uint32_t meta[16][3][16];
    int blk = blockIdx.x;
    if ((nblk & 7) == 0) {                      // XCD-chunked swizzle over Morton ranges
        int cpx = nblk >> 3;
        blk = (blk & 7) * cpx + (blk >> 3);
    }
    int base = blk * 16;
    int t = threadIdx.x;
    if (t < 16) {
        int i = base + t;
        pts[t] = (i < N) ? sorted[i] : make_float4(0.f, 0.f, 0.f, __uint_as_float(0u));
    }
    __syncthreads();
    if (t < 64 && (t & 3) < 3) {   // one thread per (point, plane)
        int pt = t >> 2, p = t & 3;
        float4 c = pts[pt];
        float gx = (p == 0) ? c.y : c.x;
        float gy = (p == 2) ? c.y : c.z;
        float ci = (p == 0) ? c.x : ((p == 1) ? c.y : c.z);
        float ix = (gx + 1.f) * 127.5f;
        float iy = (gy + 1.f) * 127.5f;
        float x0f = floorf(ix), y0f = floorf(iy);
        float wx = ix - x0f, wy = iy - y0f;
        int x0 = min(max((int)x0f, 0), HWDIM - 1);
        int y0 = min(max((int)y0f, 0), HWDIM - 1);
        int x1 = min(x0 + 1, HWDIM - 1);
        int y1 = min(y0 + 1, HWDIM - 1);
        uint32_t* m = meta[pt][p];
        float cv = (ci + 1.f) * 127.5f + 0.5f;
        float bb[9];
#pragma unroll
        for (int r = 0; r < 9; ++r) {
            const float k = 3.14159265358979f * ((float)(1 << r) - 0.5f) * (1.f / 512.f);
            bb[r] = __cosf(cv * k);
        }
#pragma unroll
        for (int j = 0; j < 4; ++j) m[j] = f2h(bb[2 * j]) | (f2h(bb[2 * j + 1]) << 16);
        m[4] = __float_as_uint(bb[8]);
        m[5] = __float_as_uint((1.f - wx) * (1.f - wy));
        m[6] = __float_as_uint(wx * (1.f - wy));
        m[7] = __float_as_uint((1.f - wx) * wy);
        m[8] = __float_as_uint(wx * wy);
        m[9]  = (uint32_t)(y0 * HWDIM + x0) * 256u;
        m[10] = (uint32_t)(y0 * HWDIM + x1) * 256u;
        m[11] = (uint32_t)(y1 * HWDIM + x0) * 256u;
        m[12] = (uint32_t)(y1 * HWDIM + x1) * 256u;
    }
    __syncthreads();
    int pt = t >> 4, cc = t & 15;
    int gi = base + pt;
    if (gi >= N) return;
    float acc = 0.f;
    const char* Ab = (const char*)A;
    const char* Bb = (const char*)B;
#pragma unroll
    for (int p = 0; p < 3; ++p) {
        const uint32_t* m = meta[pt][p];
        half2_t b01 = u2h(m[0]), b23 = u2h(m[1]), b45 = u2h(m[2]), b67 = u2h(m[3]);
        float b8 = __uint_as_float(m[4]);
        const char* Apl = Ab + (size_t)p * ((size_t)POSN * 256);
        const char* Bpl = Bb + (size_t)p * ((size_t)POSN * 32);
        float ps = 0.f;
#pragma unroll
        for (int k = 0; k < 4; ++k) {
            uint32_t ob = m[9 + k];
            uint4 a = *(const uint4*)(Apl + ob + cc * 16);        // 16 lanes read 256 B contiguous
            uint32_t bw = *(const uint32_t*)(Bpl + (ob >> 3) + ((cc >> 1) << 2));
            float v8 = h2f((cc & 1) ? (bw >> 16) : (bw & 0xffffu));
            float s = b8 * v8;
            s = DOT2(u2h(a.x), b01, s);
            s = DOT2(u2h(a.y), b23, s);
            s = DOT2(u2h(a.z), b45, s);
            s = DOT2(u2h(a.w), b67, s);
            ps = fmaf(__uint_as_float(m[5 + k]), s, ps);
        }
        acc += ps;
    }
    uint32_t n = __float_as_uint(pts[pt].w);
    out[(size_t)n * CHN + cc] = 2.f * acc;
}

// ---------- fallback: direct gather from (C,H,W) f32 ----------
__global__ __launch_bounds__(256) void triplane_direct(const float* __restrict__ coords,
                                                       const float* __restrict__ Pu,
                                                       const float* __restrict__ Pv,
                                                       const float* __restrict__ Pw,
                                                       float* __restrict__ out, int N) {
    int tid = blockIdx.x * blockDim.x + threadIdx.x;
    int n = tid >> 4;
    if (n >= N) return;
    int cc = tid & 15;
    float c0 = coords[3 * n + 0];
    float c1 = coords[3 * n + 1];
    float c2 = coords[3 * n + 2];
    float acc = 0.f;
#pragma unroll
    for (int p = 0; p < 3; ++p) {
        const float* P = (p == 0) ? Pu : ((p == 1) ? Pv : Pw);
        float gx = (p == 0) ? c1 : c0;
        float gy = (p == 2) ? c1 : c2;
        float ci = (p == 0) ? c0 : ((p == 1) ? c1 : c2);
        float ix = (gx + 1.f) * 127.5f;
        float iy = (gy + 1.f) * 127.5f;
        float x0f = floorf(ix), y0f = floorf(iy);
        float wx = ix - x0f, wy = iy - y0f;
        int x0 = min(max((int)x0f, 0), HWDIM - 1);
        int y0 = min(max((int)y0f, 0), HWDIM - 1);
        int x1 = min(x0 + 1, HWDIM - 1);
        int y1 = min(y0 + 1, HWDIM - 1);
        float cv = (ci + 1.f) * 127.5f + 0.5f;
        float w00 = (1.f - wx) * (1.f - wy), w01 = wx * (1.f - wy);
        float w10 = (1.f - wx) * wy, w11 = wx * wy;
        int p00 = y0 * HWDIM + x0, p01 = y0 * HWDIM + x1;
        int p10 = y1 * HWDIM + x0, p11 = y1 * HWDIM + x1;
#pragma unroll
        for (int r = 0; r < RF; ++r) {
            const float k = 3.14159265358979f * ((float)(1 << r) - 0.5f) / 512.f;
            float b = __cosf(cv * k);
            const float* Pc = P + (size_t)(cc * RF + r) * POSN;
            float v = w00 * Pc[p00] + w01 * Pc[p01] + w10 * Pc[p10] + w11 * Pc[p11];
            acc = fmaf(b, v, acc);
        }
    }
    out[(size_t)n * CHN + cc] = 2.f * acc;
}

extern "C" void kernel_launch(void* const* d_in, const int* in_sizes, int n_in,
                              void* d_out, int out_size, void* d_ws, size_t ws_size,
                              hipStream_t stream) {
    const float* coords = (const float*)d_in[0];
    const float* Pu = (const float*)d_in[1];
    const float* Pv = (const float*)d_in[2];
    const float* Pw = (const float*)d_in[3];
    float* out = (float*)d_out;
    int N = in_sizes[0] / 3;

    size_t offA = 0;
    size_t szA = (size_t)3 * POSN * CHN * sizeof(uint4);        // 48 MB
    size_t offB = offA + szA;
    size_t szB = (size_t)3 * POSN * 8 * sizeof(uint32_t);       // 6 MB
    size_t offS = offB + szB;
    size_t szS = (size_t)N * sizeof(float4);                    // 8 MB @ N=524288
    size_t offH = offS + szS;
    size_t szH = (size_t)NBINS * sizeof(uint32_t);              // 128 KB
    size_t need = offH + szH;

    if (ws_size >= need) {
        char* ws = (char*)d_ws;
        uint4* A = (uint4*)(ws + offA);
        uint32_t* B = (uint32_t*)(ws + offB);
        float4* sorted = (float4*)(ws + offS);
        uint32_t* hist = (uint32_t*)(ws + offH);

        hipMemsetAsync(hist, 0, szH, stream);
        int tblk = (3 * POSN) / 256;                 // 768
        int hblk = (N + 255) / 256;                  // 2048
        prep_kernel<<<tblk + hblk, 256, 0, stream>>>(Pu, Pv, Pw, A, B, coords, hist, N, tblk);
        scan_kernel<<<1, 1024, 0, stream>>>(hist);
        scatter_kernel<<<(N + 255) / 256, 256, 0, stream>>>(coords, hist, sorted, N);

        int nblk = (N + 15) / 16;
        triplane_f16<<<nblk, 256, 0, stream>>>(sorted, A, B, out, N, nblk);
    } else {
        int threads = N * CHN;
        triplane_direct<<<(threads + 255) / 256, 256, 0, stream>>>(coords, Pu, Pv, Pw, out, N);
    }
}

// Round 4
// 167.231 us; speedup vs baseline: 2.1356x; 1.0284x over previous
//
#include <hip/hip_runtime.h>
#include <hip/hip_bf16.h>

#define CHN 16
#define RF 9
#define HWDIM 256
#define POSN (HWDIM * HWDIM)
#define NBINS 32768   // 5 bits per axis, 3D Morton

typedef _Float16 half2_t __attribute__((ext_vector_type(2)));

__device__ __forceinline__ half2_t u2h(uint32_t u) {
    union { uint32_t u; half2_t h; } x; x.u = u; return x.h;
}
__device__ __forceinline__ uint32_t f2h(float f) {
    union { _Float16 h; uint16_t u; } x; x.h = (_Float16)f; return (uint32_t)x.u;
}
__device__ __forceinline__ float h2f(uint32_t u) {
    union { uint16_t u; _Float16 h; } x; x.u = (uint16_t)u; return (float)x.h;
}

#if __has_builtin(__builtin_amdgcn_fdot2)
__device__ __forceinline__ float DOT2(half2_t a, half2_t b, float c) {
    return __builtin_amdgcn_fdot2(a, b, c, false);
}
#else
__device__ __forceinline__ float DOT2(half2_t a, half2_t b, float c) {
    return fmaf((float)a.x, (float)b.x, fmaf((float)a.y, (float)b.y, c));
}
#endif

// ---------- Morton helpers ----------
__device__ __forceinline__ uint32_t part1by2(uint32_t x) {
    x &= 0x3ffu;
    x = (x | (x << 16)) & 0x030000FFu;
    x = (x | (x << 8))  & 0x0300F00Fu;
    x = (x | (x << 4))  & 0x030C30C3u;
    x = (x | (x << 2))  & 0x09249249u;
    return x;
}
__device__ __forceinline__ uint32_t morton_key(float c0, float c1, float c2) {
    int q0 = min(31, max(0, (int)((c0 + 1.f) * 16.f)));
    int q1 = min(31, max(0, (int)((c1 + 1.f) * 16.f)));
    int q2 = min(31, max(0, (int)((c2 + 1.f) * 16.f)));
    return (part1by2((uint32_t)q0) << 2) | (part1by2((uint32_t)q1) << 1) | part1by2((uint32_t)q2);
}

// ---------- pass 1: LDS-staged transpose/pack to f16 (+ fused histogram) ----------
// A: [p][pos][cc] uint4 = f16 freqs r0..r7 packed in pairs (16 B per (pos,cc))
// B: [p][pos][cc>>1] u32 = f16 r8 for channel pair (lo=even cc, hi=odd cc)
// tile = 128 consecutive pos, 128 threads. Reads pos-major (coalesced 256B/wave-instr),
// writes staged through padded LDS so global stores are fully linear/coalesced.
__global__ __launch_bounds__(128) void prep_kernel(const float* __restrict__ Pu,
                                                   const float* __restrict__ Pv,
                                                   const float* __restrict__ Pw,
                                                   uint4* __restrict__ A,
                                                   uint32_t* __restrict__ B,
                                                   const float* __restrict__ coords,
                                                   uint32_t* __restrict__ hist,
                                                   int N, int tblk) {
    __shared__ uint4 LA[128 * 17];       // stride 17 uint4 (pad) -> <=8-way ds b128 = free
    __shared__ uint32_t LB[128 * 9];     // stride 9 words (pad) -> 2-way = free
    int b = blockIdx.x;
    int t = threadIdx.x;
    if (b < tblk) {
        int tile = b;
        int p = tile >> 9;                     // POSN/128 = 512 tiles per plane
        int pos_base = (tile & 511) * 128;
        const float* P = (p == 0) ? Pu : ((p == 1) ? Pv : Pw);
        uint32_t r8pk[8];
        const float* Pc0 = P + pos_base + t;
#pragma unroll
        for (int cc = 0; cc < CHN; ++cc) {
            const float* Pc = Pc0 + (size_t)(cc * RF) * POSN;   // lanes contiguous: 256B/instr
            uint32_t w[4];
#pragma unroll
            for (int j = 0; j < 4; ++j) {
                float v0 = Pc[(size_t)(2 * j) * POSN];
                float v1 = Pc[(size_t)(2 * j + 1) * POSN];
                w[j] = f2h(v0) | (f2h(v1) << 16);
            }
            LA[t * 17 + cc] = make_uint4(w[0], w[1], w[2], w[3]);
            uint32_t h8 = f2h(Pc[(size_t)8 * POSN]);
            if (cc & 1) r8pk[cc >> 1] |= (h8 << 16); else r8pk[cc >> 1] = h8;
        }
#pragma unroll
        for (int j = 0; j < 8; ++j) LB[t * 9 + j] = r8pk[j];
        __syncthreads();
        // linear dump: fully coalesced global stores
        uint4* Aout = A + ((size_t)p * POSN + pos_base) * CHN;
#pragma unroll
        for (int it = 0; it < 16; ++it) {
            int i = it * 128 + t;                         // 2048 uint4
            Aout[i] = LA[(i >> 4) * 17 + (i & 15)];
        }
        uint32_t* Bout = B + ((size_t)p * POSN + pos_base) * 8;
#pragma unroll
        for (int it = 0; it < 8; ++it) {
            int i = it * 128 + t;                         // 1024 words
            Bout[i] = LB[(i >> 3) * 9 + (i & 7)];
        }
    } else {
        int n = (b - tblk) * 128 + t;
        if (n < N) {
            float c0 = coords[3 * n], c1 = coords[3 * n + 1], c2 = coords[3 * n + 2];
            atomicAdd(&hist[morton_key(c0, c1, c2)], 1u);
        }
    }
}

__global__ __launch_bounds__(1024) void scan_kernel(uint32_t* __restrict__ hist) {
    __shared__ uint32_t part[1024];
    int t = threadIdx.x;
    uint32_t loc[32];
    uint32_t s = 0;
    int base = t * 32;
#pragma unroll
    for (int i = 0; i < 32; ++i) { loc[i] = hist[base + i]; s += loc[i]; }
    part[t] = s;
    __syncthreads();
    for (int off = 1; off < 1024; off <<= 1) {
        uint32_t v = (t >= off) ? part[t - off] : 0u;
        __syncthreads();
        part[t] += v;
        __syncthreads();
    }
    uint32_t run = part[t] - s;
#pragma unroll
    for (int i = 0; i < 32; ++i) { hist[base + i] = run; run += loc[i]; }
}

__global__ __launch_bounds__(256) void scatter_kernel(const float* __restrict__ coords,
                                                      uint32_t* __restrict__ hist,
                                                      float4* __restrict__ sorted, int N) {
    int n = blockIdx.x * blockDim.x + threadIdx.x;
    if (n >= N) return;
    float c0 = coords[3 * n], c1 = coords[3 * n + 1], c2 = coords[3 * n + 2];
    uint32_t key = morton_key(c0, c1, c2);
    uint32_t dst = atomicAdd(&hist[key], 1u);
    sorted[dst] = make_float4(c0, c1, c2, __uint_as_float((uint32_t)n));
}

// ---------- pass 3: main ----------
// 32 points/block, 2 points/thread (slot, slot+16). meta stride 40 words (pad -> 2-way max).
// meta[pt*40 + p*13 + idx]: [0..3] f16x2 basis r0..7, [4] b8 f32, [5..8] weights f32,
//                           [9..12] corner byte offsets (pos*256)
__global__ __launch_bounds__(256) void triplane_f16v2(const float4* __restrict__ sorted,
                                                      const uint4* __restrict__ A,
                                                      const uint32_t* __restrict__ B,
                                                      float* __restrict__ out, int N, int nblk) {
    __shared__ float4 pts[32];
    __shared__ uint32_t meta[32 * 40];
    int blk = blockIdx.x;
    {   // bijective XCD-chunked swizzle (contiguous Morton range per XCD)
        int q = nblk >> 3, r = nblk & 7;
        int xcd = blk & 7, local = blk >> 3;
        blk = (xcd < r ? xcd * (q + 1) : r * (q + 1) + (xcd - r) * q) + local;
    }
    int base = blk * 32;
    int t = threadIdx.x;
    if (t < 32) {
        int i = base + t;
        pts[t] = (i < N) ? sorted[i] : make_float4(0.f, 0.f, 0.f, __uint_as_float(0u));
    }
    __syncthreads();
    if (t < 128 && (t & 3) < 3) {   // one thread per (point, plane)
        int pt = t >> 2, p = t & 3;
        float4 c = pts[pt];
        float gx = (p == 0) ? c.y : c.x;
        float gy = (p == 2) ? c.y : c.z;
        float ci = (p == 0) ? c.x : ((p == 1) ? c.y : c.z);
        float ix = (gx + 1.f) * 127.5f;
        float iy = (gy + 1.f) * 127.5f;
        float x0f = floorf(ix), y0f = floorf(iy);
        float wx = ix - x0f, wy = iy - y0f;
        int x0 = min(max((int)x0f, 0), HWDIM - 1);
        int y0 = min(max((int)y0f, 0), HWDIM - 1);
        int x1 = min(x0 + 1, HWDIM - 1);
        int y1 = min(y0 + 1, HWDIM - 1);
        uint32_t* m = &meta[pt * 40 + p * 13];
        float cv = (ci + 1.f) * 127.5f + 0.5f;
        float bb[9];
#pragma unroll
        for (int r = 0; r < 9; ++r) {
            const float k = 3.14159265358979f * ((float)(1 << r) - 0.5f) * (1.f / 512.f);
            bb[r] = __cosf(cv * k);
        }
#pragma unroll
        for (int j = 0; j < 4; ++j) m[j] = f2h(bb[2 * j]) | (f2h(bb[2 * j + 1]) << 16);
        m[4] = __float_as_uint(bb[8]);
        m[5] = __float_as_uint((1.f - wx) * (1.f - wy));
        m[6] = __float_as_uint(wx * (1.f - wy));
        m[7] = __float_as_uint((1.f - wx) * wy);
        m[8] = __float_as_uint(wx * wy);
        m[9]  = (uint32_t)(y0 * HWDIM + x0) * 256u;
        m[10] = (uint32_t)(y0 * HWDIM + x1) * 256u;
        m[11] = (uint32_t)(y1 * HWDIM + x0) * 256u;
        m[12] = (uint32_t)(y1 * HWDIM + x1) * 256u;
    }
    __syncthreads();
    int cc = t & 15, slot = t >> 4;
    const char* Ab = (const char*)A;
    const char* Bb = (const char*)B;
#pragma unroll
    for (int half = 0; half < 2; ++half) {
        int pt = slot + half * 16;
        int gi = base + pt;
        float acc = 0.f;
#pragma unroll
        for (int p = 0; p < 3; ++p) {
            const uint32_t* m = &meta[pt * 40 + p * 13];
            half2_t b01 = u2h(m[0]), b23 = u2h(m[1]), b45 = u2h(m[2]), b67 = u2h(m[3]);
            float b8 = __uint_as_float(m[4]);
            const char* Apl = Ab + (size_t)p * ((size_t)POSN * 256);
            const char* Bpl = Bb + (size_t)p * ((size_t)POSN * 32);
            float ps = 0.f;
#pragma unroll
            for (int k = 0; k < 4; ++k) {
                uint32_t ob = m[9 + k];
                uint4 a = *(const uint4*)(Apl + ob + cc * 16);    // 16 lanes read 256B contiguous
                uint32_t bw = *(const uint32_t*)(Bpl + (ob >> 3) + ((cc >> 1) << 2));
                float v8 = h2f((cc & 1) ? (bw >> 16) : (bw & 0xffffu));
                float s = b8 * v8;
                s = DOT2(u2h(a.x), b01, s);
                s = DOT2(u2h(a.y), b23, s);
                s = DOT2(u2h(a.z), b45, s);
                s = DOT2(u2h(a.w), b67, s);
                ps = fmaf(__uint_as_float(m[5 + k]), s, ps);
            }
            acc += ps;
        }
        if (gi < N) {
            uint32_t n = __float_as_uint(pts[pt].w);
            out[(size_t)n * CHN + cc] = 2.f * acc;
        }
    }
}

// ---------- fallback: direct gather from (C,H,W) f32 ----------
__global__ __launch_bounds__(256) void triplane_direct(const float* __restrict__ coords,
                                                       const float* __restrict__ Pu,
                                                       const float* __restrict__ Pv,
                                                       const float* __restrict__ Pw,
                                                       float* __restrict__ out, int N) {
    int tid = blockIdx.x * blockDim.x + threadIdx.x;
    int n = tid >> 4;
    if (n >= N) return;
    int cc = tid & 15;
    float c0 = coords[3 * n + 0];
    float c1 = coords[3 * n + 1];
    float c2 = coords[3 * n + 2];
    float acc = 0.f;
#pragma unroll
    for (int p = 0; p < 3; ++p) {
        const float* P = (p == 0) ? Pu : ((p == 1) ? Pv : Pw);
        float gx = (p == 0) ? c1 : c0;
        float gy = (p == 2) ? c1 : c2;
        float ci = (p == 0) ? c0 : ((p == 1) ? c1 : c2);
        float ix = (gx + 1.f) * 127.5f;
        float iy = (gy + 1.f) * 127.5f;
        float x0f = floorf(ix), y0f = floorf(iy);
        float wx = ix - x0f, wy = iy - y0f;
        int x0 = min(max((int)x0f, 0), HWDIM - 1);
        int y0 = min(max((int)y0f, 0), HWDIM - 1);
        int x1 = min(x0 + 1, HWDIM - 1);
        int y1 = min(y0 + 1, HWDIM - 1);
        float cv = (ci + 1.f) * 127.5f + 0.5f;
        float w00 = (1.f - wx) * (1.f - wy), w01 = wx * (1.f - wy);
        float w10 = (1.f - wx) * wy, w11 = wx * wy;
        int p00 = y0 * HWDIM + x0, p01 = y0 * HWDIM + x1;
        int p10 = y1 * HWDIM + x0, p11 = y1 * HWDIM + x1;
#pragma unroll
        for (int r = 0; r < RF; ++r) {
            const float k = 3.14159265358979f * ((float)(1 << r) - 0.5f) / 512.f;
            float b = __cosf(cv * k);
            const float* Pc = P + (size_t)(cc * RF + r) * POSN;
            float v = w00 * Pc[p00] + w01 * Pc[p01] + w10 * Pc[p10] + w11 * Pc[p11];
            acc = fmaf(b, v, acc);
        }
    }
    out[(size_t)n * CHN + cc] = 2.f * acc;
}

extern "C" void kernel_launch(void* const* d_in, const int* in_sizes, int n_in,
                              void* d_out, int out_size, void* d_ws, size_t ws_size,
                              hipStream_t stream) {
    const float* coords = (const float*)d_in[0];
    const float* Pu = (const float*)d_in[1];
    const float* Pv = (const float*)d_in[2];
    const float* Pw = (const float*)d_in[3];
    float* out = (float*)d_out;
    int N = in_sizes[0] / 3;

    size_t offA = 0;
    size_t szA = (size_t)3 * POSN * CHN * sizeof(uint4);        // 48 MB
    size_t offB = offA + szA;
    size_t szB = (size_t)3 * POSN * 8 * sizeof(uint32_t);       // 6 MB
    size_t offS = offB + szB;
    size_t szS = (size_t)N * sizeof(float4);                    // 8 MB @ N=524288
    size_t offH = offS + szS;
    size_t szH = (size_t)NBINS * sizeof(uint32_t);              // 128 KB
    size_t need = offH + szH;

    if (ws_size >= need) {
        char* ws = (char*)d_ws;
        uint4* A = (uint4*)(ws + offA);
        uint32_t* B = (uint32_t*)(ws + offB);
        float4* sorted = (float4*)(ws + offS);
        uint32_t* hist = (uint32_t*)(ws + offH);

        hipMemsetAsync(hist, 0, szH, stream);
        int tblk = (3 * POSN) / 128;                 // 1536
        int hblk = (N + 127) / 128;                  // 4096
        prep_kernel<<<tblk + hblk, 128, 0, stream>>>(Pu, Pv, Pw, A, B, coords, hist, N, tblk);
        scan_kernel<<<1, 1024, 0, stream>>>(hist);
        scatter_kernel<<<(N + 255) / 256, 256, 0, stream>>>(coords, hist, sorted, N);

        int nblk = (N + 31) / 32;                    // 16384
        triplane_f16v2<<<nblk, 256, 0, stream>>>(sorted, A, B, out, N, nblk);
    } else {
        int threads = N * CHN;
        triplane_direct<<<(threads + 255) / 256, 256, 0, stream>>>(coords, Pu, Pv, Pw, out, N);
    }
}